// Round 1
// baseline (1474.241 us; speedup 1.0000x reference)
//
#include <hip/hip_runtime.h>
#include <hip/hip_bf16.h>
#include <stdint.h>

// Problem constants (QuantizedLinear: B=4,S=2048,D_IN=4096,D_OUT=11008)
#define M_DIM 8192
#define N_DIM 11008
#define K_DIM 4096
#define BM 128
#define BN 128
#define BK 32

typedef __bf16 bf16_8 __attribute__((ext_vector_type(8)));
typedef float f32x4 __attribute__((ext_vector_type(4)));

// ---------------- fp32 -> bf16 (RNE) conversion, 8 elems/thread ----------------
__device__ __forceinline__ uint32_t pack_bf2(float lo, float hi) {
    uint32_t ulo = __float_as_uint(lo);
    uint32_t uhi = __float_as_uint(hi);
    ulo = (ulo + 0x7fffu + ((ulo >> 16) & 1u)) >> 16;
    uhi = (uhi + 0x7fffu + ((uhi >> 16) & 1u)) >> 16;
    return ulo | (uhi << 16);
}

__global__ __launch_bounds__(256) void cvt_f32_bf16(const float* __restrict__ src,
                                                    uint32_t* __restrict__ dst, int n8) {
    int i = blockIdx.x * 256 + threadIdx.x;
    if (i >= n8) return;
    const float4* s = (const float4*)src;
    float4 a = s[2 * i];
    float4 b = s[2 * i + 1];
    uint4 o;
    o.x = pack_bf2(a.x, a.y);
    o.y = pack_bf2(a.z, a.w);
    o.z = pack_bf2(b.x, b.y);
    o.w = pack_bf2(b.z, b.w);
    ((uint4*)dst)[i] = o;
}

// ---------------- async global->LDS, 16B per lane ----------------
__device__ __forceinline__ void load_lds16(const __bf16* g, __bf16* l) {
    __builtin_amdgcn_global_load_lds(
        (__attribute__((address_space(1))) void*)(g),
        (__attribute__((address_space(3))) void*)(l),
        16, 0, 0);
}

// ---------------- GEMM: C[m][n] = (A[m][:] . W[n][:]) * scale[n] + bias[n] ----------------
// A: M x K bf16 (row-major, K contiguous); W: N x K bf16 (row-major, K contiguous)
__global__ __launch_bounds__(256) void gemm_bt_scaled(
    const __bf16* __restrict__ A, const __bf16* __restrict__ W,
    const float* __restrict__ scale, const float* __restrict__ bias,
    float* __restrict__ C) {
    __shared__ __align__(16) __bf16 As[BM * BK];
    __shared__ __align__(16) __bf16 Bs[BN * BK];

    const int t = threadIdx.x;
    const int wave = t >> 6;
    const int lane = t & 63;
    const int wm = wave >> 1;   // wave row in 2x2 wave grid
    const int wn = wave & 1;    // wave col

    const int m0 = blockIdx.y * BM;
    const int n0 = blockIdx.x * BN;

    // staging addresses: per issue, wave covers 16 rows x 32 k
    const int srow = lane >> 2;          // 0..15
    const int skk = (lane & 3) * 8;      // 0,8,16,24

    const __bf16* Ag = A + (long)(m0 + wave * 16 + srow) * K_DIM + skk;
    const __bf16* Wg = W + (long)(n0 + wave * 16 + srow) * K_DIM + skk;
    __bf16* AsW = &As[(wave * 16) * BK];   // wave-uniform LDS base
    __bf16* BsW = &Bs[(wave * 16) * BK];

    f32x4 acc[4][4] = {};

    const int lrow = lane & 15;          // fragment row (m or n within 16)
    const int lk = (lane >> 4) * 8;      // k offset within 32

    for (int k0 = 0; k0 < K_DIM; k0 += BK) {
        __syncthreads();   // previous iteration's LDS reads complete
        load_lds16(Ag + k0, AsW);
        load_lds16(Ag + (long)64 * K_DIM + k0, AsW + 64 * BK);
        load_lds16(Wg + k0, BsW);
        load_lds16(Wg + (long)64 * K_DIM + k0, BsW + 64 * BK);
        __syncthreads();   // vmcnt(0) drain before barrier -> tiles ready

        bf16_8 af[4], bfr[4];
#pragma unroll
        for (int i = 0; i < 4; i++)
            af[i] = *(const bf16_8*)&As[(wm * 64 + i * 16 + lrow) * BK + lk];
#pragma unroll
        for (int j = 0; j < 4; j++)
            bfr[j] = *(const bf16_8*)&Bs[(wn * 64 + j * 16 + lrow) * BK + lk];
#pragma unroll
        for (int i = 0; i < 4; i++)
#pragma unroll
            for (int j = 0; j < 4; j++)
                acc[i][j] = __builtin_amdgcn_mfma_f32_16x16x32_bf16(af[i], bfr[j], acc[i][j], 0, 0, 0);
    }

    // Epilogue: C/D layout col = lane&15, row = (lane>>4)*4 + reg  [m89/m91 verified]
    const int crow4 = (lane >> 4) * 4;
    const int ccol = lane & 15;
#pragma unroll
    for (int j = 0; j < 4; j++) {
        const int n = n0 + wn * 64 + j * 16 + ccol;
        const float sc = scale[n];
        const float bi = bias[n];
#pragma unroll
        for (int i = 0; i < 4; i++) {
            const int mbase = m0 + wm * 64 + i * 16 + crow4;
#pragma unroll
            for (int r = 0; r < 4; r++) {
                C[(long)(mbase + r) * N_DIM + n] = acc[i][j][r] * sc + bi;
            }
        }
    }
}

extern "C" void kernel_launch(void* const* d_in, const int* in_sizes, int n_in,
                              void* d_out, int out_size, void* d_ws, size_t ws_size,
                              hipStream_t stream) {
    const float* x = (const float*)d_in[0];       // [M, K] fp32
    const float* w_q = (const float*)d_in[1];     // [N, K] fp32 (fp8-representable)
    const float* scale = (const float*)d_in[2];   // [N]
    const float* bias = (const float*)d_in[3];    // [N]
    float* out = (float*)d_out;                   // [M, N] fp32

    // Workspace layout: x_bf16 (64 MB) | w_bf16 (86 MB)
    __bf16* x_bf = (__bf16*)d_ws;
    __bf16* w_bf = (__bf16*)((char*)d_ws + (size_t)M_DIM * K_DIM * sizeof(__bf16));

    const int n8x = (M_DIM * K_DIM) / 8;
    const int n8w = (N_DIM * K_DIM) / 8;
    cvt_f32_bf16<<<(n8x + 255) / 256, 256, 0, stream>>>(x, (uint32_t*)x_bf, n8x);
    cvt_f32_bf16<<<(n8w + 255) / 256, 256, 0, stream>>>(w_q, (uint32_t*)w_bf, n8w);

    dim3 grid(N_DIM / BN, M_DIM / BM);  // 86 x 64
    gemm_bt_scaled<<<grid, 256, 0, stream>>>(x_bf, w_bf, scale, bias, out);
}

// Round 2
// 1454.280 us; speedup vs baseline: 1.0137x; 1.0137x over previous
//
#include <hip/hip_runtime.h>
#include <hip/hip_bf16.h>
#include <stdint.h>

// Problem constants (QuantizedLinear: B=4,S=2048,D_IN=4096,D_OUT=11008)
#define M_DIM 8192
#define N_DIM 11008
#define K_DIM 4096
#define BM 128
#define BN 128
#define BK 32

typedef __bf16 bf16_8 __attribute__((ext_vector_type(8)));
typedef float f32x4 __attribute__((ext_vector_type(4)));

// ---------------- fp32 -> bf16 (RNE) conversion, 4 elems/thread, fully coalesced ----------------
__device__ __forceinline__ uint32_t pack_bf2(float lo, float hi) {
    uint32_t ulo = __float_as_uint(lo);
    uint32_t uhi = __float_as_uint(hi);
    ulo = (ulo + 0x7fffu + ((ulo >> 16) & 1u)) >> 16;
    uhi = (uhi + 0x7fffu + ((uhi >> 16) & 1u)) >> 16;
    return ulo | (uhi << 16);
}

__global__ __launch_bounds__(256) void cvt_f32_bf16(const float* __restrict__ src,
                                                    uint2* __restrict__ dst, int n4) {
    int i = blockIdx.x * 256 + threadIdx.x;
    if (i >= n4) return;
    float4 a = ((const float4*)src)[i];   // 16B/lane, consecutive lanes contiguous
    uint2 o;
    o.x = pack_bf2(a.x, a.y);
    o.y = pack_bf2(a.z, a.w);
    dst[i] = o;                            // 8B/lane, contiguous
}

// ---------------- async global->LDS, 16B per lane ----------------
__device__ __forceinline__ void load_lds16(const __bf16* g, __bf16* l) {
    __builtin_amdgcn_global_load_lds(
        (__attribute__((address_space(1))) void*)(g),
        (__attribute__((address_space(3))) void*)(l),
        16, 0, 0);
}

// ---------------- GEMM: C[m][n] = (A[m][:] . W[n][:]) * scale[n] + bias[n] ----------------
// A: M x K bf16 (row-major); W: N x K bf16 (row-major)
// LDS k-chunk XOR swizzle: slot c of LDS row r holds global k-chunk c ^ ((r>>1)&3).
// This spreads each wave's ds_read_b128 across all 8 16B-slots per 128B bank line
// (exactly 8 accesses/slot = minimum bank cycles); destination stays lane-contiguous
// as global_load_lds requires (we permute the SOURCE address per lane instead).
__global__ __launch_bounds__(256) void gemm_bt_scaled(
    const __bf16* __restrict__ A, const __bf16* __restrict__ W,
    const float* __restrict__ scale, const float* __restrict__ bias,
    float* __restrict__ C) {
    __shared__ __align__(16) __bf16 As[BM * BK];
    __shared__ __align__(16) __bf16 Bs[BN * BK];

    const int t = threadIdx.x;
    const int wave = t >> 6;
    const int lane = t & 63;
    const int wm = wave >> 1;   // wave row in 2x2 wave grid
    const int wn = wave & 1;    // wave col

    const int m0 = blockIdx.y * BM;
    const int n0 = blockIdx.x * BN;

    // staging: lane l covers (row = l>>2, k-chunk = (l&3) ^ ((l>>3)&3)) of a 16x32 tile
    const int srow = lane >> 2;                            // 0..15
    const int skk = ((lane & 3) ^ ((lane >> 3) & 3)) * 8;  // swizzled k-chunk, elements

    const __bf16* Ag = A + (long)(m0 + wave * 16 + srow) * K_DIM + skk;
    const __bf16* Wg = W + (long)(n0 + wave * 16 + srow) * K_DIM + skk;
    __bf16* AsW = &As[(wave * 16) * BK];   // wave-uniform LDS base
    __bf16* BsW = &Bs[(wave * 16) * BK];

    f32x4 acc[4][4] = {};

    const int lrow = lane & 15;                     // fragment row (m or n within 16)
    const int swz = (lrow >> 1) & 3;                // row-dependent slot XOR
    const int lk = ((lane >> 4) ^ swz) * 8;         // swizzled k offset within 32

    for (int k0 = 0; k0 < K_DIM; k0 += BK) {
        __syncthreads();   // previous iteration's LDS reads complete
        load_lds16(Ag + k0, AsW);
        load_lds16(Ag + (long)64 * K_DIM + k0, AsW + 64 * BK);
        load_lds16(Wg + k0, BsW);
        load_lds16(Wg + (long)64 * K_DIM + k0, BsW + 64 * BK);
        __syncthreads();   // drain before use -> tiles ready

        bf16_8 af[4], bfr[4];
#pragma unroll
        for (int i = 0; i < 4; i++)
            af[i] = *(const bf16_8*)&As[(wm * 64 + i * 16 + lrow) * BK + lk];
#pragma unroll
        for (int j = 0; j < 4; j++)
            bfr[j] = *(const bf16_8*)&Bs[(wn * 64 + j * 16 + lrow) * BK + lk];
#pragma unroll
        for (int i = 0; i < 4; i++)
#pragma unroll
            for (int j = 0; j < 4; j++)
                acc[i][j] = __builtin_amdgcn_mfma_f32_16x16x32_bf16(af[i], bfr[j], acc[i][j], 0, 0, 0);
    }

    // Epilogue: C/D layout col = lane&15, row = (lane>>4)*4 + reg  [m89/m91 verified]
    const int crow4 = (lane >> 4) * 4;
    const int ccol = lane & 15;
#pragma unroll
    for (int j = 0; j < 4; j++) {
        const int n = n0 + wn * 64 + j * 16 + ccol;
        const float sc = scale[n];
        const float bi = bias[n];
#pragma unroll
        for (int i = 0; i < 4; i++) {
            const int mbase = m0 + wm * 64 + i * 16 + crow4;
#pragma unroll
            for (int r = 0; r < 4; r++) {
                C[(long)(mbase + r) * N_DIM + n] = acc[i][j][r] * sc + bi;
            }
        }
    }
}

extern "C" void kernel_launch(void* const* d_in, const int* in_sizes, int n_in,
                              void* d_out, int out_size, void* d_ws, size_t ws_size,
                              hipStream_t stream) {
    const float* x = (const float*)d_in[0];       // [M, K] fp32
    const float* w_q = (const float*)d_in[1];     // [N, K] fp32 (fp8-representable)
    const float* scale = (const float*)d_in[2];   // [N]
    const float* bias = (const float*)d_in[3];    // [N]
    float* out = (float*)d_out;                   // [M, N] fp32

    // Workspace layout: x_bf16 (64 MB) | w_bf16 (86 MB)
    __bf16* x_bf = (__bf16*)d_ws;
    __bf16* w_bf = (__bf16*)((char*)d_ws + (size_t)M_DIM * K_DIM * sizeof(__bf16));

    const int n4x = (M_DIM * K_DIM) / 4;
    const int n4w = (N_DIM * K_DIM) / 4;
    cvt_f32_bf16<<<(n4x + 255) / 256, 256, 0, stream>>>(x, (uint2*)x_bf, n4x);
    cvt_f32_bf16<<<(n4w + 255) / 256, 256, 0, stream>>>(w_q, (uint2*)w_bf, n4w);

    dim3 grid(N_DIM / BN, M_DIM / BM);  // 86 x 64
    gemm_bt_scaled<<<grid, 256, 0, stream>>>(x_bf, w_bf, scale, bias, out);
}